// Round 1
// baseline (72.169 us; speedup 1.0000x reference)
//
#include <hip/hip_runtime.h>

// GiniLoss: gini = sum_{i,j} |x_i - x_j| / (2 * n^2 * mu)
// where mu = mean(x - min(x)) + EPS if min(x) < 0 else mean(x) + EPS.
// Key identity: the min-shift cancels inside |xf_i - xf_j|, so the O(n^2)
// pairwise sum needs only raw x. n = 8192 -> x fits in 32 KB LDS.

#define EPS 1e-8f

// Kernel A: per-block partial of sum_{i,j}|x_i - x_j|.
// grid = ceil(n*8 / 256) blocks, 256 threads. Thread g: row = g>>3,
// column float4-chunks c = (g&7) + 8k  (seg in LOW bits -> the 8 distinct
// LDS addresses per wave are 16B apart -> span all 32 banks, 8-lane
// broadcast each -> conflict-free ds_read_b128).
__global__ void __launch_bounds__(256) gini_pair_partial(
    const float* __restrict__ x, float* __restrict__ partials, int n) {
    __shared__ __align__(16) float sm[8192];
    for (int i = threadIdx.x; i < n; i += 256) sm[i] = x[i];
    __syncthreads();

    int g   = blockIdx.x * 256 + threadIdx.x;
    int row = g >> 3;
    int seg = g & 7;
    float acc = 0.0f;
    if (row < n) {
        float xi = sm[row];
        const float4* sm4 = (const float4*)sm;
        int nchunks = n >> 2;
        for (int c = seg; c < nchunks; c += 8) {
            float4 v = sm4[c];
            acc += fabsf(xi - v.x);
            acc += fabsf(xi - v.y);
            acc += fabsf(xi - v.z);
            acc += fabsf(xi - v.w);
        }
    }
    // wave (64) reduce, then cross-wave via LDS
    #pragma unroll
    for (int off = 32; off > 0; off >>= 1) acc += __shfl_down(acc, off, 64);
    __shared__ float wsum[4];
    int wave = threadIdx.x >> 6;
    if ((threadIdx.x & 63) == 0) wsum[wave] = acc;
    __syncthreads();
    if (threadIdx.x == 0)
        partials[blockIdx.x] = wsum[0] + wsum[1] + wsum[2] + wsum[3];
}

// Kernel B: reduce min(x), sum(x), sum(partials); compute gini scalar.
__global__ void __launch_bounds__(256) gini_finalize(
    const float* __restrict__ x, const float* __restrict__ partials,
    int nblocks, float* __restrict__ out, int n) {
    float lmin = 3.4e38f, lsum = 0.0f, psum = 0.0f;
    for (int i = threadIdx.x; i < n; i += 256) {
        float v = x[i];
        lmin = fminf(lmin, v);
        lsum += v;
    }
    for (int i = threadIdx.x; i < nblocks; i += 256) psum += partials[i];

    #pragma unroll
    for (int off = 32; off > 0; off >>= 1) {
        lmin = fminf(lmin, __shfl_down(lmin, off, 64));
        lsum += __shfl_down(lsum, off, 64);
        psum += __shfl_down(psum, off, 64);
    }
    __shared__ float smin[4], ssum[4], spsum[4];
    int wave = threadIdx.x >> 6;
    if ((threadIdx.x & 63) == 0) {
        smin[wave] = lmin; ssum[wave] = lsum; spsum[wave] = psum;
    }
    __syncthreads();
    if (threadIdx.x == 0) {
        float mn = fminf(fminf(smin[0], smin[1]), fminf(smin[2], smin[3]));
        float sum = ssum[0] + ssum[1] + ssum[2] + ssum[3];
        float sd  = spsum[0] + spsum[1] + spsum[2] + spsum[3];
        // reference: shift only applied when min < 0 (abs-diffs unaffected)
        float shifted_sum = (mn < 0.0f) ? (sum - (float)n * mn) : sum;
        float mu = shifted_sum / (float)n + EPS;
        out[0] = sd / (2.0f * (float)n * (float)n * mu);
    }
}

extern "C" void kernel_launch(void* const* d_in, const int* in_sizes, int n_in,
                              void* d_out, int out_size, void* d_ws, size_t ws_size,
                              hipStream_t stream) {
    const float* x = (const float*)d_in[0];
    float* out = (float*)d_out;
    float* partials = (float*)d_ws;
    int n = in_sizes[0];

    int nblocks = (n * 8 + 255) / 256;  // 8 column-threads per row
    gini_pair_partial<<<nblocks, 256, 0, stream>>>(x, partials, n);
    gini_finalize<<<1, 256, 0, stream>>>(x, partials, nblocks, out, n);
}

// Round 2
// 64.510 us; speedup vs baseline: 1.1187x; 1.1187x over previous
//
#include <hip/hip_runtime.h>

// GiniLoss: gini = sum_{i,j} |x_i - x_j| / (2 * n^2 * mu)
// where mu = mean(x - min(x)) + EPS if min(x) < 0 else mean(x) + EPS.
// The min-shift cancels inside |xf_i - xf_j| so the pairwise sum uses raw x.
// n = 8192 -> x fits in 32 KB LDS.
//
// R2: register-block 8 rows per thread (8x less LDS traffic -> VALU-bound),
// 512 blocks (2/CU, 8 waves/CU) for latency hiding.

#define EPS 1e-8f

// Each "row group" = 8 consecutive rows, handled by 128 column-threads.
// Thread: rows in VGPRs, scans n/128 columns as float4 (stride-1 b128 within
// a wave -> conflict-free broadcast-friendly LDS pattern).
__global__ void __launch_bounds__(256) gini_pair_partial(
    const float* __restrict__ x, float* __restrict__ partials, int n) {
    __shared__ __align__(16) float sm[8192];
    const int nchunks = n >> 2;  // 2048 float4 chunks
    {
        const float4* xv = (const float4*)x;
        float4* smv = (float4*)sm;
        for (int i = threadIdx.x; i < nchunks; i += 256) smv[i] = xv[i];
    }
    __syncthreads();

    int g     = blockIdx.x * 256 + threadIdx.x;
    int group = g >> 7;      // 8-row group index
    int seg   = g & 127;     // column-thread within group
    int row0  = group * 8;

    float acc0 = 0.f, acc1 = 0.f, acc2 = 0.f, acc3 = 0.f;
    float acc4 = 0.f, acc5 = 0.f, acc6 = 0.f, acc7 = 0.f;
    if (row0 + 7 < n) {
        float r0 = sm[row0 + 0], r1 = sm[row0 + 1];
        float r2 = sm[row0 + 2], r3 = sm[row0 + 3];
        float r4 = sm[row0 + 4], r5 = sm[row0 + 5];
        float r6 = sm[row0 + 6], r7 = sm[row0 + 7];
        const float4* sm4 = (const float4*)sm;
        #pragma unroll 4
        for (int c = seg; c < nchunks; c += 128) {
            float4 v = sm4[c];
            // 2-level add tree per acc: shortens the dependent chain
            acc0 += (fabsf(r0 - v.x) + fabsf(r0 - v.y)) + (fabsf(r0 - v.z) + fabsf(r0 - v.w));
            acc1 += (fabsf(r1 - v.x) + fabsf(r1 - v.y)) + (fabsf(r1 - v.z) + fabsf(r1 - v.w));
            acc2 += (fabsf(r2 - v.x) + fabsf(r2 - v.y)) + (fabsf(r2 - v.z) + fabsf(r2 - v.w));
            acc3 += (fabsf(r3 - v.x) + fabsf(r3 - v.y)) + (fabsf(r3 - v.z) + fabsf(r3 - v.w));
            acc4 += (fabsf(r4 - v.x) + fabsf(r4 - v.y)) + (fabsf(r4 - v.z) + fabsf(r4 - v.w));
            acc5 += (fabsf(r5 - v.x) + fabsf(r5 - v.y)) + (fabsf(r5 - v.z) + fabsf(r5 - v.w));
            acc6 += (fabsf(r6 - v.x) + fabsf(r6 - v.y)) + (fabsf(r6 - v.z) + fabsf(r6 - v.w));
            acc7 += (fabsf(r7 - v.x) + fabsf(r7 - v.y)) + (fabsf(r7 - v.z) + fabsf(r7 - v.w));
        }
    }
    float acc = ((acc0 + acc1) + (acc2 + acc3)) + ((acc4 + acc5) + (acc6 + acc7));

    #pragma unroll
    for (int off = 32; off > 0; off >>= 1) acc += __shfl_down(acc, off, 64);
    __shared__ float wsum[4];
    int wave = threadIdx.x >> 6;
    if ((threadIdx.x & 63) == 0) wsum[wave] = acc;
    __syncthreads();
    if (threadIdx.x == 0)
        partials[blockIdx.x] = (wsum[0] + wsum[1]) + (wsum[2] + wsum[3]);
}

// Kernel B: reduce min(x), sum(x), sum(partials); compute gini scalar.
__global__ void __launch_bounds__(256) gini_finalize(
    const float* __restrict__ x, const float* __restrict__ partials,
    int nblocks, float* __restrict__ out, int n) {
    float lmin = 3.4e38f, lsum = 0.0f, psum = 0.0f;
    for (int i = threadIdx.x; i < n; i += 256) {
        float v = x[i];
        lmin = fminf(lmin, v);
        lsum += v;
    }
    for (int i = threadIdx.x; i < nblocks; i += 256) psum += partials[i];

    #pragma unroll
    for (int off = 32; off > 0; off >>= 1) {
        lmin = fminf(lmin, __shfl_down(lmin, off, 64));
        lsum += __shfl_down(lsum, off, 64);
        psum += __shfl_down(psum, off, 64);
    }
    __shared__ float smin[4], ssum[4], spsum[4];
    int wave = threadIdx.x >> 6;
    if ((threadIdx.x & 63) == 0) {
        smin[wave] = lmin; ssum[wave] = lsum; spsum[wave] = psum;
    }
    __syncthreads();
    if (threadIdx.x == 0) {
        float mn  = fminf(fminf(smin[0], smin[1]), fminf(smin[2], smin[3]));
        float sum = (ssum[0] + ssum[1]) + (ssum[2] + ssum[3]);
        float sd  = (spsum[0] + spsum[1]) + (spsum[2] + spsum[3]);
        float shifted_sum = (mn < 0.0f) ? (sum - (float)n * mn) : sum;
        float mu = shifted_sum / (float)n + EPS;
        out[0] = sd / (2.0f * (float)n * (float)n * mu);
    }
}

extern "C" void kernel_launch(void* const* d_in, const int* in_sizes, int n_in,
                              void* d_out, int out_size, void* d_ws, size_t ws_size,
                              hipStream_t stream) {
    const float* x = (const float*)d_in[0];
    float* out = (float*)d_out;
    float* partials = (float*)d_ws;
    int n = in_sizes[0];

    // threads needed = (n/8 groups) * 128 col-threads = n*16
    int nblocks = (n * 16 + 255) / 256;  // 512 for n=8192 -> 2 blocks/CU
    gini_pair_partial<<<nblocks, 256, 0, stream>>>(x, partials, n);
    gini_finalize<<<1, 256, 0, stream>>>(x, partials, nblocks, out, n);
}